// Round 3
// baseline (92.628 us; speedup 1.0000x reference)
//
#include <hip/hip_runtime.h>
#include <hip/hip_bf16.h>

#define AA_NUM 21
#define A_NUM  14
#define NPTS   4096    // 16^3
#define BLK    512
#define PPT    (NPTS / BLK)   // 8 points per thread

// Broadcast a block-uniform float into an SGPR.
__device__ __forceinline__ float rfl(float x) {
    return __int_as_float(__builtin_amdgcn_readfirstlane(__float_as_int(x)));
}

__global__ __launch_bounds__(BLK) void preproc_kernel(
    const float* __restrict__ Cin,   // [ZN][14][3] f32
    const int*   __restrict__ Lin,   // [ZN] i32
    const float* __restrict__ Min,   // [ZN][14] f32 atom_mask
    const float* __restrict__ Qin,   // [21][14] f32 charges
    float*       __restrict__ out,   // f32: Cb | div | frames
    int ZN)
{
    __shared__ float s_atom[A_NUM][3];
    __shared__ float s_pc[A_NUM];
    __shared__ float s_fr[12];        // frames row-major [u*3+s] + origin
    __shared__ float s_f[3][NPTS];    // normalized field components fx,fy,fz

    const int n = blockIdx.x;
    const int t = threadIdx.x;
    const size_t div_off = (size_t)ZN * 12;
    const size_t fr_off  = div_off + (size_t)ZN * NPTS;

    // ---- stage atoms + pc into LDS ----
    if (t < A_NUM) {
        int la = Lin[n];
        la = (la == -1) ? (AA_NUM - 1) : la;
        float q = Qin[la * A_NUM + t];
        float m = Min[n * A_NUM + t];
        s_pc[t] = q * m;
        s_atom[t][0] = Cin[(n * A_NUM + t) * 3 + 0];
        s_atom[t][1] = Cin[(n * A_NUM + t) * 3 + 1];
        s_atom[t][2] = Cin[(n * A_NUM + t) * 3 + 2];
    }
    __syncthreads();

    // ---- backbone + frames (thread 0) ----
    if (t == 0) {
        const float c0 = 0.58273431f, c1 = 0.56802827f, c2 = 0.54067466f;
        float n0x = s_atom[0][0], n0y = s_atom[0][1], n0z = s_atom[0][2];
        float cax = s_atom[1][0], cay = s_atom[1][1], caz = s_atom[1][2];
        float ccx = s_atom[2][0], ccy = s_atom[2][1], ccz = s_atom[2][2];
        float b1x = cax - n0x, b1y = cay - n0y, b1z = caz - n0z;
        float b2x = ccx - cax, b2y = ccy - cay, b2z = ccz - caz;
        float b3x = b1y * b2z - b1z * b2y;
        float b3y = b1z * b2x - b1x * b2z;
        float b3z = b1x * b2y - b1y * b2x;
        float cbx = cax - c0 * b2x + c1 * b1x - c2 * b3x;
        float cby = cay - c0 * b2y + c1 * b1y - c2 * b3y;
        float cbz = caz - c0 * b2z + c1 * b1z - c2 * b3z;

        float* po = out + (size_t)n * 12;
        po[0]  = n0x; po[1]  = n0y; po[2]  = n0z;
        po[3]  = cax; po[4]  = cay; po[5]  = caz;
        po[6]  = ccx; po[7]  = ccy; po[8]  = ccz;
        po[9]  = cbx; po[10] = cby; po[11] = cbz;

        // frames: y = cb - ca
        float yx = cbx - cax, yy = cby - cay, yz = cbz - caz;
        float yn = sqrtf(yx * yx + yy * yy + yz * yz);
        float yr = 1.0f / fmaxf(yn, 1e-6f);
        float yux = yx * yr, yuy = yy * yr, yuz = yz * yr;
        // x_raw = C - N;  x = x_raw - dot(x_raw, y_unit)  (scalar broadcast, per reference!)
        float xrx = ccx - n0x, xry = ccy - n0y, xrz = ccz - n0z;
        float xp = xrx * yux + xry * yuy + xrz * yuz;
        float xx = xrx - xp, xy = xry - xp, xz = xrz - xp;
        float xn = sqrtf(xx * xx + xy * xy + xz * xz);
        float xr = 1.0f / fmaxf(xn, 1e-6f);
        float xux = xx * xr, xuy = xy * xr, xuz = xz * xr;
        float zx = xuy * yuz - xuz * yuy;
        float zy = xuz * yux - xux * yuz;
        float zz = xux * yuy - xuy * yux;
        float zn = sqrtf(zx * zx + zy * zy + zz * zz);
        float zr = 1.0f / fmaxf(zn, 1e-6f);
        float zux = zx * zr, zuy = zy * zr, zuz = zz * zr;

        float* pf = out + fr_off + (size_t)n * 9;
        pf[0] = xux; pf[1] = xuy; pf[2] = xuz;
        pf[3] = yux; pf[4] = yuy; pf[5] = yuz;
        pf[6] = zux; pf[7] = zuy; pf[8] = zuz;

        s_fr[0] = xux; s_fr[1] = xuy; s_fr[2]  = xuz;
        s_fr[3] = yux; s_fr[4] = yuy; s_fr[5]  = yuz;
        s_fr[6] = zux; s_fr[7] = zuy; s_fr[8]  = zuz;
        s_fr[9] = cbx; s_fr[10] = cby; s_fr[11] = cbz;
    }
    __syncthreads();

    // ---- broadcast block-uniform data into SGPRs ----
    float ax[A_NUM], ay[A_NUM], az[A_NUM], aq[A_NUM];
    #pragma unroll
    for (int a = 0; a < A_NUM; ++a) {
        ax[a] = rfl(s_atom[a][0]);
        ay[a] = rfl(s_atom[a][1]);
        az[a] = rfl(s_atom[a][2]);
        aq[a] = rfl(s_pc[a]);
    }
    float fr[12];
    #pragma unroll
    for (int i = 0; i < 12; ++i) fr[i] = s_fr[i];

    // ---- field accumulation per voxel point ----
    #pragma unroll
    for (int k = 0; k < PPT; ++k) {
        int idx = t + k * BLK;
        float vx = (float)(idx >> 8) - 8.0f;
        float vy = (float)((idx >> 4) & 15) - 4.0f;
        float vz = (float)(idx & 15) - 8.0f;
        float px = fr[9]  + vx * fr[0] + vy * fr[3] + vz * fr[6];
        float py = fr[10] + vx * fr[1] + vy * fr[4] + vz * fr[7];
        float pz = fr[11] + vx * fr[2] + vy * fr[5] + vz * fr[8];
        float fx = 0.0f, fy = 0.0f, fz = 0.0f;
        #pragma unroll
        for (int a = 0; a < A_NUM; ++a) {
            float dx = px - ax[a], dy = py - ay[a], dz = pz - az[a];
            float d2 = dx * dx + dy * dy + dz * dz;
            float rq = __builtin_amdgcn_rsqf(d2);   // 1/d
            // 1 / (d * max(d,1)^2) == rq * min(rq,1)^2
            float mn = fminf(rq, 1.0f);
            float inv = rq * mn * mn;
            float w = (d2 != 0.0f) ? aq[a] * inv : 0.0f;
            fx = fmaf(w, dx, fx);
            fy = fmaf(w, dy, fy);
            fz = fmaf(w, dz, fz);
        }
        float fn2 = fx * fx + fy * fy + fz * fz;
        float rf = (fn2 != 0.0f) ? __builtin_amdgcn_rsqf(fn2) : 1.0f;
        s_f[0][idx] = fx * rf;
        s_f[1][idx] = fy * rf;
        s_f[2][idx] = fz * rf;
    }
    __syncthreads();

    // ---- divergence from LDS fields ----
    float* dout = out + div_off + (size_t)n * NPTS;
    #pragma unroll
    for (int k = 0; k < PPT; ++k) {
        int idx = t + k * BLK;
        int xi = idx >> 8, yi = (idx >> 4) & 15, zi = idx & 15;
        int xm = xi - (xi > 0), xp = xi + (xi < 15);
        int ym = yi - (yi > 0), yp = yi + (yi < 15);
        int zm = zi - (zi > 0), zp = zi + (zi < 15);
        float sx = (xp - xm == 2) ? 0.5f : 1.0f;
        float sy = (yp - ym == 2) ? 0.5f : 1.0f;
        float sz = (zp - zm == 2) ? 0.5f : 1.0f;
        int byz = (yi << 4) | zi;
        int bxz = (xi << 8) | zi;
        int bxy = (xi << 8) | (yi << 4);
        float dxv = (s_f[0][(xp << 8) | byz] - s_f[0][(xm << 8) | byz]) * sx;
        float dyv = (s_f[1][bxz | (yp << 4)] - s_f[1][bxz | (ym << 4)]) * sy;
        float dzv = (s_f[2][bxy | zp]        - s_f[2][bxy | zm])        * sz;
        dout[idx] = dxv + dyv + dzv;
    }
}

extern "C" void kernel_launch(void* const* d_in, const int* in_sizes, int n_in,
                              void* d_out, int out_size, void* d_ws, size_t ws_size,
                              hipStream_t stream) {
    const float* C = (const float*)d_in[0];
    const int*   L = (const int*)d_in[1];
    const float* M = (const float*)d_in[2];
    const float* Q = (const float*)d_in[3];
    float* out = (float*)d_out;
    const int ZN = in_sizes[1];   // L has one entry per residue
    preproc_kernel<<<dim3(ZN), dim3(BLK), 0, stream>>>(C, L, M, Q, out, ZN);
}